// Round 4
// baseline (780.741 us; speedup 1.0000x reference)
//
#include <hip/hip_runtime.h>

// ---- problem constants ----
#define HW     9216
#define NTOK   18432

typedef float  floatx4 __attribute__((ext_vector_type(4)));
typedef short  short8  __attribute__((ext_vector_type(8)));
typedef short  short4v __attribute__((ext_vector_type(4)));
typedef int    int4v   __attribute__((ext_vector_type(4)));

#if __has_builtin(__builtin_amdgcn_exp2f)
#define EXP2F(x) __builtin_amdgcn_exp2f(x)
#else
#define EXP2F(x) exp2f(x)
#endif

__device__ __forceinline__ unsigned short f2bf(float f) {   // RNE
  unsigned int u = __float_as_uint(f);
  u += 0x7fffu + ((u >> 16) & 1u);
  return (unsigned short)(u >> 16);
}
__device__ __forceinline__ float bf2f(unsigned short s) {
  return __uint_as_float(((unsigned int)s) << 16);
}
// pack two floats to bf16x2 (round-half-away) -- used in k_qkv/k_post
__device__ __forceinline__ int pk2(float a, float b) {
  unsigned ua = __float_as_uint(a) + 0x8000u;
  unsigned ub = __float_as_uint(b) + 0x8000u;
  return (int)((ua >> 16) | (ub & 0xffff0000u));
}
// single-instruction pack (RNE), gfx950 v_cvt_pk_bf16_f32: 5 VALU -> 1
__device__ __forceinline__ int cvtpk(float a, float b) {
  int r;
  asm("v_cvt_pk_bf16_f32 %0, %1, %2" : "=v"(r) : "v"(a), "v"(b));
  return r;
}

// ======================================================================
// k_qkv: UNCHANGED (LN1 + MFMA Q/K/V projections, weights staged bf16
// in LDS, vector stores; output formats frozen). Split-count agnostic.
// ======================================================================
__global__ __launch_bounds__(256) void k_qkv(
    const float* __restrict__ x,
    const float* __restrict__ wq, const float* __restrict__ bq,
    const float* __restrict__ wk, const float* __restrict__ bk,
    const float* __restrict__ wv, const float* __restrict__ bv,
    const float* __restrict__ g1, const float* __restrict__ b1,
    const int* __restrict__ mask,
    const float* __restrict__ wo, const float* __restrict__ w1,
    const float* __restrict__ w2,
    unsigned short* __restrict__ h_bf, unsigned short* __restrict__ qg,
    unsigned short* __restrict__ ksw, unsigned short* __restrict__ vsw,
    float* __restrict__ maskf, unsigned short* __restrict__ wobf,
    unsigned short* __restrict__ w1bf, unsigned short* __restrict__ w2bf,
    float* __restrict__ cntb)
{
  // overlay: x-tile (8448 B) lives only until LN is done; then the same
  // region holds the bf16 weights wb[3][64][72] (27648 B).
  __shared__ __align__(16) char usmem[27648];
  float (*xt)[33] = (float (*)[33])usmem;
  unsigned short (*wb)[64][72] = (unsigned short (*)[64][72])usmem;

  __shared__ unsigned short hq[32][72];   // h bf16 [tok][ch]
  __shared__ unsigned short kt[32][72];
  __shared__ unsigned short vt[64][40];
  __shared__ unsigned short qt[32][72];
  __shared__ float mk32[32];

  const int tid = threadIdx.x, wid = tid >> 6, c = tid & 63;
  const int mcol = c & 15, quad = c >> 4;
  const int bx = blockIdx.x;
  const int t0 = bx * 32;
  const int b  = t0 / HW, n0 = t0 % HW;

  if (tid < 32) {
    const float m = mask[t0 + tid] ? 1.f : 0.f;
    maskf[t0 + tid] = m;
    mk32[tid] = m;
  }
  // per-block masked-token count (wave 0 ballot; every slot written)
  if (wid == 0) {
    const bool mm = (c < 32) ? (mask[t0 + c] == 0) : false;
    const unsigned long long bal = __ballot(mm);
    if (c == 0) cntb[bx] = (float)__popcll(bal);
  }
  if (bx < 16)       { const int i = bx * 256 + tid;        wobf[i] = f2bf(wo[i]); }
  else if (bx < 80)  { const int i = (bx - 16) * 256 + tid; w1bf[i] = f2bf(w1[i]); }
  else if (bx < 144) { const int i = (bx - 80) * 256 + tid; w2bf[i] = f2bf(w2[i]); }

  #pragma unroll
  for (int p = 0; p < 2; ++p) {
    const int idx = p * 256 + tid;
    const int cc = idx >> 3, t4 = (idx & 7) * 4;
    const floatx4 v = *(const floatx4*)(x + ((long)b * 64 + cc) * HW + n0 + t4);
    xt[cc][t4 + 0] = v[0]; xt[cc][t4 + 1] = v[1];
    xt[cc][t4 + 2] = v[2]; xt[cc][t4 + 3] = v[3];
  }
  __syncthreads();

  // LN1: lane = channel, 8 tokens per wave (unchanged numerics)
  {
    const float g1v = g1[c], b1v = b1[c];
    #pragma unroll
    for (int tt = 0; tt < 8; ++tt) {
      const int tok = wid * 8 + tt;
      const float val = xt[c][tok];
      float s = val, q = val * val;
      #pragma unroll
      for (int d = 1; d < 64; d <<= 1) { s += __shfl_xor(s, d); q += __shfl_xor(q, d); }
      const float mu  = s * (1.f / 64.f);
      const float var = q * (1.f / 64.f) - mu * mu;
      const float hv  = (val - mu) * rsqrtf(var + 1e-5f) * g1v + b1v;
      hq[tok][c] = f2bf(hv);
    }
  }
  __syncthreads();   // hq ready; xt dead -> usmem reusable as wb

  // h_bf vector store (overlaps the wb fill below)
  {
    const int tok = tid >> 3, c8 = (tid & 7) * 8;
    *(short8*)(h_bf + (long)(t0 + tok) * 64 + c8) = *(const short8*)(&hq[tok][c8]);
  }

  // stage wq/wk/wv as bf16 into LDS, fully coalesced (12 x 16B loads/thread)
  {
    auto conv = [&](const float* __restrict__ W, int mwi) {
      #pragma unroll
      for (int j = 0; j < 4; ++j) {
        const int idx4 = (j * 256 + tid) * 4;      // 0..4095 step 4
        const int o = idx4 >> 6, in4 = idx4 & 63;
        const floatx4 w4 = *(const floatx4*)(W + idx4);
        short4v s4;
        s4[0] = (short)f2bf(w4[0]); s4[1] = (short)f2bf(w4[1]);
        s4[2] = (short)f2bf(w4[2]); s4[3] = (short)f2bf(w4[3]);
        *(short4v*)(&wb[mwi][o][in4]) = s4;
      }
    };
    conv(wq, 0); conv(wk, 1); conv(wv, 2);
  }
  __syncthreads();

  // MFMA projections: 24 output tiles (3 mats x 2 tokTiles x 4 outTiles),
  // 6 per wave. D[tokT*16+quad*4+r][outT*16+mcol] = sum_k h[tok][k]*W[out][k].
  {
    const float QSC = 0.125f * 1.44269504088896f;   // C^-0.5 * log2(e)
    #pragma unroll
    for (int i = 0; i < 6; ++i) {
      const int t = wid * 6 + i;
      const int mat  = t >> 3;          // 0:Q 1:K 2:V (uniform per wave-iter)
      const int tokT = (t >> 2) & 1;
      const int outT = t & 3;
      const int out  = outT * 16 + mcol;
      const short8 A0 = *(const short8*)(&hq[tokT * 16 + mcol][quad * 8]);
      const short8 A1 = *(const short8*)(&hq[tokT * 16 + mcol][32 + quad * 8]);
      const short8 B0 = *(const short8*)(&wb[mat][out][quad * 8]);
      const short8 B1 = *(const short8*)(&wb[mat][out][32 + quad * 8]);
      floatx4 d = (floatx4){0.f, 0.f, 0.f, 0.f};
      d = __builtin_amdgcn_mfma_f32_16x16x32_bf16(A0, B0, d, 0, 0, 0);
      d = __builtin_amdgcn_mfma_f32_16x16x32_bf16(A1, B1, d, 0, 0, 0);
      if (mat == 0) {
        const float bias = bq[out];
        #pragma unroll
        for (int r = 0; r < 4; ++r) {
          const int tok = tokT * 16 + quad * 4 + r;
          qt[tok][out] = f2bf((d[r] + bias) * QSC);
        }
      } else if (mat == 1) {
        const float bias = bk[out];
        #pragma unroll
        for (int r = 0; r < 4; ++r) {
          const int tok = tokT * 16 + quad * 4 + r;
          kt[tok][out] = f2bf((d[r] + bias) * mk32[tok]);   // mask fold
        }
      } else {
        const float bias = bv[out];
        #pragma unroll
        for (int r = 0; r < 4; ++r) {
          const int tok = tokT * 16 + quad * 4 + r;
          vt[out][tok] = f2bf((d[r] + bias) * mk32[tok]);   // mask fold
        }
      }
    }
  }
  __syncthreads();

  // qg vector store
  {
    const int tok = tid >> 3, c8 = (tid & 7) * 8;
    *(short8*)(qg + (long)(t0 + tok) * 64 + c8) = *(const short8*)(&qt[tok][c8]);
  }

  const long tile = (long)b * 288 + (n0 >> 5);
  {
    const int slot = tid >> 6, l = tid & 63;
    const int m = l & 15, qd = l >> 4, sub = slot >> 1, ss = slot & 1;
    const short8 v8 = *(const short8*)(&kt[sub * 16 + m][ss * 32 + qd * 8]);
    *(short8*)(ksw + tile * 2048 + tid * 8) = v8;
  }
  {
    // V with key-slot permutation: slot (qd, j): j<4 -> key 4qd+j (sub0),
    // j>=4 -> key 16+4qd+(j-4) (sub1). Two contiguous b64 reads.
    const int f = tid >> 6, l = tid & 63;
    const int m = l & 15, qd = l >> 4;
    const short4v lo = *(const short4v*)(&vt[f * 16 + m][qd * 4]);
    const short4v hi = *(const short4v*)(&vt[f * 16 + m][16 + qd * 4]);
    short8 v8;
    v8[0] = lo[0]; v8[1] = lo[1]; v8[2] = lo[2]; v8[3] = lo[3];
    v8[4] = hi[0]; v8[5] = hi[1]; v8[6] = hi[2]; v8[7] = hi[3];
    *(short8*)(vsw + tile * 2048 + tid * 8) = v8;
  }
}

// ======================================================================
// k_attn (ROUND-3): templated on split count NS. NS=16 doubles resident
// waves (3->6 waves/SIMD) so the QK-MFMA -> exp2 -> pack -> PV-MFMA
// chain of one wave hides under another wave's MFMA (round-2 showed 20%
// dual-idle at 3 waves/SIMD). pk2 (5 VALU) -> v_cvt_pk_bf16_f32 (1 VALU)
// on the hot path; s_setprio(1) around MFMA clusters (T5). Direct-global
// fragment reads (no LDS staging) kept from round 2.
// ======================================================================
template <int NS>
__global__ __launch_bounds__(256, (NS >= 16) ? 6 : 3) void k_attn(
    const unsigned short* __restrict__ qg, const unsigned short* __restrict__ ksw,
    const unsigned short* __restrict__ vsw,
    unsigned short* __restrict__ opart, float* __restrict__ lpart)
{
  constexpr int KITN = HW / NS / 32;   // tiles of 32 keys per split
  // LDS only for the epilogue per-wave fp32 transpose scratch
  __shared__ __align__(16) char smem[17408];

  const int tid = threadIdx.x, wid = tid >> 6, lane = tid & 63;
  const int mcol = lane & 15, quad = lane >> 4;
  const int bx = blockIdx.x;
  const int split = bx % NS, qidx = bx / NS;   // qidx 0..95
  const int b = qidx / 48, qt = qidx % 48;
  const long t0q = (long)b * HW + qt * 192 + wid * 48;

  const unsigned short* kswt = ksw + ((long)b * 288 + split * KITN) * 2048;
  const unsigned short* vswt = vsw + ((long)b * 288 + split * KITN) * 2048;

  short8 qf[3][2];
  #pragma unroll
  for (int g = 0; g < 3; ++g)
    #pragma unroll
    for (int s = 0; s < 2; ++s)
      qf[g][s] = *(const short8*)(qg + (t0q + g * 16 + mcol) * 64 + s * 32 + quad * 8);

  short8 ones8;
  #pragma unroll
  for (int i = 0; i < 8; ++i) ones8[i] = (short)0x3F80;   // bf16 1.0

  floatx4 oT[3][4], oL[3];
  #pragma unroll
  for (int g = 0; g < 3; ++g) {
    #pragma unroll
    for (int f = 0; f < 4; ++f) oT[g][f] = (floatx4){0.f,0.f,0.f,0.f};
    oL[g] = (floatx4){0.f,0.f,0.f,0.f};
  }

  // K register ping-pong: preload tile 0
  short8 ka[4], kb[4];
  #pragma unroll
  for (int s = 0; s < 4; ++s)
    ka[s] = *(const short8*)(kswt + (s * 64 + lane) * 8);

#define ATTN_ITER(IT, KCUR, KNXT)                                              \
  {                                                                            \
    short8 cv[4];                                                              \
    _Pragma("unroll")                                                          \
    for (int f = 0; f < 4; ++f)                                                \
      cv[f] = *(const short8*)(vswt + (IT) * 2048 + (f * 64 + lane) * 8);      \
    if ((IT) + 1 < KITN) {                                                     \
      _Pragma("unroll")                                                        \
      for (int s = 0; s < 4; ++s)                                              \
        KNXT[s] = *(const short8*)(kswt + ((IT) + 1) * 2048 + (s * 64 + lane) * 8); \
    }                                                                          \
    short8 pf[3];                                                              \
    _Pragma("unroll")                                                          \
    for (int g = 0; g < 3; ++g) {                                              \
      floatx4 s0 = (floatx4){0.f,0.f,0.f,0.f}, s1 = (floatx4){0.f,0.f,0.f,0.f};\
      __builtin_amdgcn_s_setprio(1);                                           \
      s0 = __builtin_amdgcn_mfma_f32_16x16x32_bf16(KCUR[0], qf[g][0], s0, 0, 0, 0); \
      s0 = __builtin_amdgcn_mfma_f32_16x16x32_bf16(KCUR[1], qf[g][1], s0, 0, 0, 0); \
      s1 = __builtin_amdgcn_mfma_f32_16x16x32_bf16(KCUR[2], qf[g][0], s1, 0, 0, 0); \
      s1 = __builtin_amdgcn_mfma_f32_16x16x32_bf16(KCUR[3], qf[g][1], s1, 0, 0, 0); \
      __builtin_amdgcn_s_setprio(0);                                           \
      int4v pv;                                                                \
      pv[0] = cvtpk(EXP2F(s0[0]), EXP2F(s0[1]));                               \
      pv[1] = cvtpk(EXP2F(s0[2]), EXP2F(s0[3]));                               \
      pv[2] = cvtpk(EXP2F(s1[0]), EXP2F(s1[1]));                               \
      pv[3] = cvtpk(EXP2F(s1[2]), EXP2F(s1[3]));                               \
      pf[g] = __builtin_bit_cast(short8, pv);                                  \
      oL[g] = __builtin_amdgcn_mfma_f32_16x16x32_bf16(ones8, pf[g], oL[g], 0, 0, 0); \
    }                                                                          \
    __builtin_amdgcn_s_setprio(1);                                             \
    _Pragma("unroll")                                                          \
    for (int f = 0; f < 4; ++f) {                                              \
      _Pragma("unroll")                                                        \
      for (int g = 0; g < 3; ++g)                                              \
        oT[g][f] = __builtin_amdgcn_mfma_f32_16x16x32_bf16(cv[f], pf[g], oT[g][f], 0, 0, 0); \
    }                                                                          \
    __builtin_amdgcn_s_setprio(0);                                             \
  }

  for (int it = 0; it < KITN; it += 2) {   // KITN even (36 or 18)
    ATTN_ITER(it,     ka, kb);
    ATTN_ITER(it + 1, kb, ka);
  }
#undef ATTN_ITER

  // epilogue: per-wave fp32->bf16 transpose through LDS (per-wave
  // disjoint regions; intra-wave lockstep makes write->read safe)
  float* scr = (float*)smem + wid * 1088;    // 16 rows x 68
  #pragma unroll
  for (int g = 0; g < 3; ++g) {
    #pragma unroll
    for (int f = 0; f < 4; ++f)
      #pragma unroll
      for (int r = 0; r < 4; ++r)
        scr[(quad * 4 + r) * 68 + f * 16 + mcol] = oT[g][f][r];
    #pragma unroll
    for (int ps = 0; ps < 2; ++ps) {
      const int row = ps * 8 + (lane >> 3), cb = (lane & 7) * 8;
      const floatx4 a = *(const floatx4*)(scr + row * 68 + cb);
      const floatx4 c = *(const floatx4*)(scr + row * 68 + cb + 4);
      int4v pk;
      pk[0] = cvtpk(a[0], a[1]); pk[1] = cvtpk(a[2], a[3]);
      pk[2] = cvtpk(c[0], c[1]); pk[3] = cvtpk(c[2], c[3]);
      *(int4v*)(opart + ((long)split * NTOK + t0q + g * 16 + row) * 64 + cb) = pk;
    }
  }
  if (lane < 16) {   // quad 0 holds l[query=mcol] in oL[g][0]
    #pragma unroll
    for (int g = 0; g < 3; ++g)
      lpart[(long)split * NTOK + t0q + g * 16 + lane] = oL[g][0];
  }
}

// ======================================================================
// k_post: templated on NS (merge loop width); otherwise unchanged.
// ======================================================================
template <int NS>
__global__ __launch_bounds__(256) void k_post(
    const unsigned short* __restrict__ opart, const float* __restrict__ lpart,
    const unsigned short* __restrict__ h_bf, const float* __restrict__ maskf,
    const float* __restrict__ cntb,
    const unsigned short* __restrict__ wobf, const float* __restrict__ bo,
    const float* __restrict__ g2, const float* __restrict__ b2,
    const unsigned short* __restrict__ w1bf, const float* __restrict__ bf1,
    const unsigned short* __restrict__ w2bf, const float* __restrict__ bf2,
    float* __restrict__ out)
{
  __shared__ float          h2_lds[32 * 68];
  __shared__ unsigned short att_lds[32 * 72];
  __shared__ unsigned short hn_lds[32 * 72];
  __shared__ unsigned short g_lds[32 * 264];
  __shared__ float          ot_lds[32 * 68];
  __shared__ float          linv[32];
  __shared__ float          st_mu[32], st_rs[32];
  __shared__ float          nred[4];

  const int tid = threadIdx.x, wid = tid >> 6, lane = tid & 63;
  const int mcol = lane & 15, quad = lane >> 4;
  const int t0 = blockIdx.x * 32;
  const int b = t0 / HW, n0 = t0 % HW;

  // nmask = sum of this batch's 288 per-block counts
  {
    float cacc = 0.f;
    for (int i = tid; i < 288; i += 256) cacc += cntb[b * 288 + i];
    #pragma unroll
    for (int d = 1; d < 64; d <<= 1) cacc += __shfl_xor(cacc, d);
    if (lane == 0) nred[wid] = cacc;
  }

  const int tok = tid >> 3, c8 = (tid & 7) * 8;
  float o[8];
  #pragma unroll
  for (int i = 0; i < 8; ++i) o[i] = 0.f;
  #pragma unroll
  for (int s = 0; s < NS; ++s) {
    const short8 op = *(const short8*)(opart + ((long)s * NTOK + t0 + tok) * 64 + c8);
    #pragma unroll
    for (int i = 0; i < 8; ++i) o[i] += bf2f((unsigned short)op[i]);
  }
  const short8 hb8 = *(const short8*)(h_bf + (long)(t0 + tok) * 64 + c8);
  const floatx4 bo0 = *(const floatx4*)(bo + c8);
  const floatx4 bo1 = *(const floatx4*)(bo + c8 + 4);
  __syncthreads();

  if (tid < 32) {
    float l = -((nred[0] + nred[1]) + (nred[2] + nred[3]));   // mask-fold correction
    #pragma unroll
    for (int s = 0; s < NS; ++s) l += lpart[(long)s * NTOK + t0 + tid];
    linv[tid] = 1.0f / l;
  }
  __syncthreads();
  {
    const float sc = linv[tok];
    int4v av;
    av[0] = pk2(o[0]*sc, o[1]*sc); av[1] = pk2(o[2]*sc, o[3]*sc);
    av[2] = pk2(o[4]*sc, o[5]*sc); av[3] = pk2(o[6]*sc, o[7]*sc);
    *(int4v*)(att_lds + tok * 72 + c8) = av;
    floatx4 h20, h21;
    #pragma unroll
    for (int i = 0; i < 4; ++i) {
      h20[i] = bf2f((unsigned short)hb8[i])     + bo0[i];
      h21[i] = bf2f((unsigned short)hb8[i + 4]) + bo1[i];
    }
    *(floatx4*)(h2_lds + tok * 68 + c8)     = h20;
    *(floatx4*)(h2_lds + tok * 68 + c8 + 4) = h21;
  }
  __syncthreads();

  const int Mt = wid & 1, nbase = (wid >> 1) * 2;
  {
    const short8 aA0 = *(const short8*)(att_lds + (Mt * 16 + mcol) * 72 + quad * 8);
    const short8 aA1 = *(const short8*)(att_lds + (Mt * 16 + mcol) * 72 + 32 + quad * 8);
    #pragma unroll
    for (int nt = 0; nt < 2; ++nt) {
      const int nc = (nbase + nt) * 16;
      const short8 b0 = *(const short8*)(wobf + (nc + mcol) * 64 + quad * 8);
      const short8 b1 = *(const short8*)(wobf + (nc + mcol) * 64 + 32 + quad * 8);
      floatx4 d = (floatx4){0.f,0.f,0.f,0.f};
      d = __builtin_amdgcn_mfma_f32_16x16x32_bf16(aA0, b0, d, 0, 0, 0);
      d = __builtin_amdgcn_mfma_f32_16x16x32_bf16(aA1, b1, d, 0, 0, 0);
      #pragma unroll
      for (int r = 0; r < 4; ++r)
        h2_lds[(Mt * 16 + quad * 4 + r) * 68 + nc + mcol] += d[r];
    }
  }
  __syncthreads();

  {
    floatx4 v0 = *(const floatx4*)(h2_lds + tok * 68 + c8);
    floatx4 v1 = *(const floatx4*)(h2_lds + tok * 68 + c8 + 4);
    float s1 = (v0[0]+v0[1])+(v0[2]+v0[3]) + (v1[0]+v1[1])+(v1[2]+v1[3]);
    float s2 = (v0[0]*v0[0]+v0[1]*v0[1])+(v0[2]*v0[2]+v0[3]*v0[3])
             + (v1[0]*v1[0]+v1[1]*v1[1])+(v1[2]*v1[2]+v1[3]*v1[3]);
    #pragma unroll
    for (int d = 1; d < 8; d <<= 1) { s1 += __shfl_xor(s1, d); s2 += __shfl_xor(s2, d); }
    if ((tid & 7) == 0) {
      const float mu = s1 * (1.f / 64.f);
      const float var = s2 * (1.f / 64.f) - mu * mu;
      st_mu[tok] = mu; st_rs[tok] = rsqrtf(var + 1e-5f);
    }
  }
  __syncthreads();

  {
    const float mu = st_mu[tok], rs = st_rs[tok];
    const floatx4 v0 = *(const floatx4*)(h2_lds + tok * 68 + c8);
    const floatx4 v1 = *(const floatx4*)(h2_lds + tok * 68 + c8 + 4);
    const floatx4 ga = *(const floatx4*)(g2 + c8), gb = *(const floatx4*)(g2 + c8 + 4);
    const floatx4 ba = *(const floatx4*)(b2 + c8), bb = *(const floatx4*)(b2 + c8 + 4);
    float hn[8];
    #pragma unroll
    for (int i = 0; i < 4; ++i) {
      hn[i]     = (v0[i] - mu) * rs * ga[i] + ba[i];
      hn[i + 4] = (v1[i] - mu) * rs * gb[i] + bb[i];
    }
    int4v hv;
    hv[0] = pk2(hn[0], hn[1]); hv[1] = pk2(hn[2], hn[3]);
    hv[2] = pk2(hn[4], hn[5]); hv[3] = pk2(hn[6], hn[7]);
    *(int4v*)(hn_lds + tok * 72 + c8) = hv;
  }
  __syncthreads();

  {
    const short8 aA0 = *(const short8*)(hn_lds + (Mt * 16 + mcol) * 72 + quad * 8);
    const short8 aA1 = *(const short8*)(hn_lds + (Mt * 16 + mcol) * 72 + 32 + quad * 8);
    #pragma unroll
    for (int nt = 0; nt < 8; ++nt) {
      const int u0 = ((wid >> 1) * 8 + nt) * 16;
      const short8 b0 = *(const short8*)(w1bf + (u0 + mcol) * 64 + quad * 8);
      const short8 b1 = *(const short8*)(w1bf + (u0 + mcol) * 64 + 32 + quad * 8);
      floatx4 d = (floatx4){0.f,0.f,0.f,0.f};
      d = __builtin_amdgcn_mfma_f32_16x16x32_bf16(aA0, b0, d, 0, 0, 0);
      d = __builtin_amdgcn_mfma_f32_16x16x32_bf16(aA1, b1, d, 0, 0, 0);
      const float bf1v = bf1[u0 + mcol];
      #pragma unroll
      for (int r = 0; r < 4; ++r) {
        const float a = d[r] + bf1v;
        const float gl = 0.5f * a * (1.0f + erff(a * 0.70710678118654752f));
        g_lds[(Mt * 16 + quad * 4 + r) * 264 + u0 + mcol] = f2bf(gl);
      }
    }
  }
  __syncthreads();

  {
    floatx4 acc[2];
    acc[0] = (floatx4){0.f,0.f,0.f,0.f}; acc[1] = (floatx4){0.f,0.f,0.f,0.f};
    #pragma unroll
    for (int ks = 0; ks < 8; ++ks) {
      const short8 aA = *(const short8*)(g_lds + (Mt * 16 + mcol) * 264 + ks * 32 + quad * 8);
      #pragma unroll
      for (int nt = 0; nt < 2; ++nt) {
        const int nc = (nbase + nt) * 16;
        const short8 bB = *(const short8*)(w2bf + (nc + mcol) * 256 + ks * 32 + quad * 8);
        acc[nt] = __builtin_amdgcn_mfma_f32_16x16x32_bf16(aA, bB, acc[nt], 0, 0, 0);
      }
    }
    #pragma unroll
    for (int nt = 0; nt < 2; ++nt) {
      const int cc = (nbase + nt) * 16 + mcol;
      const float g2v = g2[cc], b2v = b2[cc], bf2v = bf2[cc];
      #pragma unroll
      for (int r = 0; r < 4; ++r) {
        const int tokr = Mt * 16 + quad * 4 + r;
        const float hn = (h2_lds[tokr * 68 + cc] - st_mu[tokr]) * st_rs[tokr] * g2v + b2v;
        const float o2 = (hn + acc[nt][r] + bf2v) * maskf[t0 + tokr];
        ot_lds[tokr * 68 + cc] = o2;
      }
    }
  }
  __syncthreads();

  {
    const int c = tid >> 2, tg = (tid & 3) * 8;
    floatx4 v0, v1;
    #pragma unroll
    for (int i = 0; i < 4; ++i) {
      v0[i] = ot_lds[(tg + i) * 68 + c];
      v1[i] = ot_lds[(tg + 4 + i) * 68 + c];
    }
    float* dst = out + ((long)b * 64 + c) * HW + n0 + tg;
    *(floatx4*)dst = v0;
    *(floatx4*)(dst + 4) = v1;
  }
}

// ======================================================================
extern "C" void kernel_launch(void* const* d_in, const int* in_sizes, int n_in,
                              void* d_out, int out_size, void* d_ws, size_t ws_size,
                              hipStream_t stream) {
  (void)in_sizes; (void)n_in; (void)out_size;
  const float* x   = (const float*)d_in[0];
  const int*   msk = (const int*)  d_in[1];
  const float* wq  = (const float*)d_in[2];
  const float* bq  = (const float*)d_in[3];
  const float* wk  = (const float*)d_in[4];
  const float* bk  = (const float*)d_in[5];
  const float* wv  = (const float*)d_in[6];
  const float* bv  = (const float*)d_in[7];
  const float* wo  = (const float*)d_in[8];
  const float* bo  = (const float*)d_in[9];
  const float* g1  = (const float*)d_in[10];
  const float* b1  = (const float*)d_in[11];
  const float* g2  = (const float*)d_in[12];
  const float* b2  = (const float*)d_in[13];
  const float* w1  = (const float*)d_in[14];
  const float* bf1 = (const float*)d_in[15];
  const float* w2  = (const float*)d_in[16];
  const float* bf2 = (const float*)d_in[17];
  float* out = (float*)d_out;

  // pick split count by available workspace (16 needs ~48.5 MB)
  auto ws_need = [](size_t S) -> size_t {
    return 4ull * 2359296 + S * NTOK * 64 * 2 + S * NTOK * 4
         + 73728 + 8192 + 32768 + 32768 + 2304;
  };
  const int S = (ws_size >= ws_need(16)) ? 16 : 8;

  char* ws = (char*)d_ws;
  size_t off = 0;
  unsigned short* h_bf  = (unsigned short*)(ws + off); off += 2359296;
  unsigned short* qg    = (unsigned short*)(ws + off); off += 2359296;
  unsigned short* ksw   = (unsigned short*)(ws + off); off += 2359296;
  unsigned short* vsw   = (unsigned short*)(ws + off); off += 2359296;
  unsigned short* opart = (unsigned short*)(ws + off); off += (size_t)S * NTOK * 64 * 2;
  float*          lpart = (float*)(ws + off);          off += (size_t)S * NTOK * 4;
  float*          maskf = (float*)(ws + off);          off += 73728;
  unsigned short* wobf  = (unsigned short*)(ws + off); off += 8192;
  unsigned short* w1bf  = (unsigned short*)(ws + off); off += 32768;
  unsigned short* w2bf  = (unsigned short*)(ws + off); off += 32768;
  float*          cntb  = (float*)(ws + off);          off += 2304;

  k_qkv<<<dim3(576), dim3(256), 0, stream>>>(
      x, wq, bq, wk, bk, wv, bv, g1, b1, msk, wo, w1, w2,
      h_bf, qg, ksw, vsw, maskf, wobf, w1bf, w2bf, cntb);
  if (S == 16) {
    k_attn<16><<<dim3(96 * 16), dim3(256), 0, stream>>>(qg, ksw, vsw, opart, lpart);
    k_post<16><<<dim3(576), dim3(256), 0, stream>>>(
        opart, lpart, h_bf, maskf, cntb, wobf, bo, g2, b2, w1bf, bf1, w2bf, bf2, out);
  } else {
    k_attn<8><<<dim3(96 * 8), dim3(256), 0, stream>>>(qg, ksw, vsw, opart, lpart);
    k_post<8><<<dim3(576), dim3(256), 0, stream>>>(
        opart, lpart, h_bf, maskf, cntb, wobf, bo, g2, b2, w1bf, bf1, w2bf, bf2, out);
  }
}

// Round 5
// 406.965 us; speedup vs baseline: 1.9184x; 1.9184x over previous
//
#include <hip/hip_runtime.h>

// ---- problem constants ----
#define HW     9216
#define NTOK   18432

typedef float  floatx4 __attribute__((ext_vector_type(4)));
typedef short  short8  __attribute__((ext_vector_type(8)));
typedef short  short4v __attribute__((ext_vector_type(4)));
typedef int    int4v   __attribute__((ext_vector_type(4)));

#if __has_builtin(__builtin_amdgcn_exp2f)
#define EXP2F(x) __builtin_amdgcn_exp2f(x)
#else
#define EXP2F(x) exp2f(x)
#endif

__device__ __forceinline__ unsigned short f2bf(float f) {   // RNE
  unsigned int u = __float_as_uint(f);
  u += 0x7fffu + ((u >> 16) & 1u);
  return (unsigned short)(u >> 16);
}
__device__ __forceinline__ float bf2f(unsigned short s) {
  return __uint_as_float(((unsigned int)s) << 16);
}
// pack two floats to bf16x2 (round-half-away) -- used in k_qkv/k_post
__device__ __forceinline__ int pk2(float a, float b) {
  unsigned ua = __float_as_uint(a) + 0x8000u;
  unsigned ub = __float_as_uint(b) + 0x8000u;
  return (int)((ua >> 16) | (ub & 0xffff0000u));
}
// single-instruction pack (RNE), gfx950 v_cvt_pk_bf16_f32: 5 VALU -> 1
__device__ __forceinline__ int cvtpk(float a, float b) {
  int r;
  asm("v_cvt_pk_bf16_f32 %0, %1, %2" : "=v"(r) : "v"(a), "v"(b));
  return r;
}

// ======================================================================
// k_qkv: UNCHANGED (LN1 + MFMA Q/K/V projections, weights staged bf16
// in LDS, vector stores; output formats frozen). Split-count agnostic.
// ======================================================================
__global__ __launch_bounds__(256) void k_qkv(
    const float* __restrict__ x,
    const float* __restrict__ wq, const float* __restrict__ bq,
    const float* __restrict__ wk, const float* __restrict__ bk,
    const float* __restrict__ wv, const float* __restrict__ bv,
    const float* __restrict__ g1, const float* __restrict__ b1,
    const int* __restrict__ mask,
    const float* __restrict__ wo, const float* __restrict__ w1,
    const float* __restrict__ w2,
    unsigned short* __restrict__ h_bf, unsigned short* __restrict__ qg,
    unsigned short* __restrict__ ksw, unsigned short* __restrict__ vsw,
    float* __restrict__ maskf, unsigned short* __restrict__ wobf,
    unsigned short* __restrict__ w1bf, unsigned short* __restrict__ w2bf,
    float* __restrict__ cntb)
{
  // overlay: x-tile (8448 B) lives only until LN is done; then the same
  // region holds the bf16 weights wb[3][64][72] (27648 B).
  __shared__ __align__(16) char usmem[27648];
  float (*xt)[33] = (float (*)[33])usmem;
  unsigned short (*wb)[64][72] = (unsigned short (*)[64][72])usmem;

  __shared__ unsigned short hq[32][72];   // h bf16 [tok][ch]
  __shared__ unsigned short kt[32][72];
  __shared__ unsigned short vt[64][40];
  __shared__ unsigned short qt[32][72];
  __shared__ float mk32[32];

  const int tid = threadIdx.x, wid = tid >> 6, c = tid & 63;
  const int mcol = c & 15, quad = c >> 4;
  const int bx = blockIdx.x;
  const int t0 = bx * 32;
  const int b  = t0 / HW, n0 = t0 % HW;

  if (tid < 32) {
    const float m = mask[t0 + tid] ? 1.f : 0.f;
    maskf[t0 + tid] = m;
    mk32[tid] = m;
  }
  // per-block masked-token count (wave 0 ballot; every slot written)
  if (wid == 0) {
    const bool mm = (c < 32) ? (mask[t0 + c] == 0) : false;
    const unsigned long long bal = __ballot(mm);
    if (c == 0) cntb[bx] = (float)__popcll(bal);
  }
  if (bx < 16)       { const int i = bx * 256 + tid;        wobf[i] = f2bf(wo[i]); }
  else if (bx < 80)  { const int i = (bx - 16) * 256 + tid; w1bf[i] = f2bf(w1[i]); }
  else if (bx < 144) { const int i = (bx - 80) * 256 + tid; w2bf[i] = f2bf(w2[i]); }

  #pragma unroll
  for (int p = 0; p < 2; ++p) {
    const int idx = p * 256 + tid;
    const int cc = idx >> 3, t4 = (idx & 7) * 4;
    const floatx4 v = *(const floatx4*)(x + ((long)b * 64 + cc) * HW + n0 + t4);
    xt[cc][t4 + 0] = v[0]; xt[cc][t4 + 1] = v[1];
    xt[cc][t4 + 2] = v[2]; xt[cc][t4 + 3] = v[3];
  }
  __syncthreads();

  // LN1: lane = channel, 8 tokens per wave (unchanged numerics)
  {
    const float g1v = g1[c], b1v = b1[c];
    #pragma unroll
    for (int tt = 0; tt < 8; ++tt) {
      const int tok = wid * 8 + tt;
      const float val = xt[c][tok];
      float s = val, q = val * val;
      #pragma unroll
      for (int d = 1; d < 64; d <<= 1) { s += __shfl_xor(s, d); q += __shfl_xor(q, d); }
      const float mu  = s * (1.f / 64.f);
      const float var = q * (1.f / 64.f) - mu * mu;
      const float hv  = (val - mu) * rsqrtf(var + 1e-5f) * g1v + b1v;
      hq[tok][c] = f2bf(hv);
    }
  }
  __syncthreads();   // hq ready; xt dead -> usmem reusable as wb

  // h_bf vector store (overlaps the wb fill below)
  {
    const int tok = tid >> 3, c8 = (tid & 7) * 8;
    *(short8*)(h_bf + (long)(t0 + tok) * 64 + c8) = *(const short8*)(&hq[tok][c8]);
  }

  // stage wq/wk/wv as bf16 into LDS, fully coalesced (12 x 16B loads/thread)
  {
    auto conv = [&](const float* __restrict__ W, int mwi) {
      #pragma unroll
      for (int j = 0; j < 4; ++j) {
        const int idx4 = (j * 256 + tid) * 4;      // 0..4095 step 4
        const int o = idx4 >> 6, in4 = idx4 & 63;
        const floatx4 w4 = *(const floatx4*)(W + idx4);
        short4v s4;
        s4[0] = (short)f2bf(w4[0]); s4[1] = (short)f2bf(w4[1]);
        s4[2] = (short)f2bf(w4[2]); s4[3] = (short)f2bf(w4[3]);
        *(short4v*)(&wb[mwi][o][in4]) = s4;
      }
    };
    conv(wq, 0); conv(wk, 1); conv(wv, 2);
  }
  __syncthreads();

  // MFMA projections: 24 output tiles (3 mats x 2 tokTiles x 4 outTiles),
  // 6 per wave. D[tokT*16+quad*4+r][outT*16+mcol] = sum_k h[tok][k]*W[out][k].
  {
    const float QSC = 0.125f * 1.44269504088896f;   // C^-0.5 * log2(e)
    #pragma unroll
    for (int i = 0; i < 6; ++i) {
      const int t = wid * 6 + i;
      const int mat  = t >> 3;          // 0:Q 1:K 2:V (uniform per wave-iter)
      const int tokT = (t >> 2) & 1;
      const int outT = t & 3;
      const int out  = outT * 16 + mcol;
      const short8 A0 = *(const short8*)(&hq[tokT * 16 + mcol][quad * 8]);
      const short8 A1 = *(const short8*)(&hq[tokT * 16 + mcol][32 + quad * 8]);
      const short8 B0 = *(const short8*)(&wb[mat][out][quad * 8]);
      const short8 B1 = *(const short8*)(&wb[mat][out][32 + quad * 8]);
      floatx4 d = (floatx4){0.f, 0.f, 0.f, 0.f};
      d = __builtin_amdgcn_mfma_f32_16x16x32_bf16(A0, B0, d, 0, 0, 0);
      d = __builtin_amdgcn_mfma_f32_16x16x32_bf16(A1, B1, d, 0, 0, 0);
      if (mat == 0) {
        const float bias = bq[out];
        #pragma unroll
        for (int r = 0; r < 4; ++r) {
          const int tok = tokT * 16 + quad * 4 + r;
          qt[tok][out] = f2bf((d[r] + bias) * QSC);
        }
      } else if (mat == 1) {
        const float bias = bk[out];
        #pragma unroll
        for (int r = 0; r < 4; ++r) {
          const int tok = tokT * 16 + quad * 4 + r;
          kt[tok][out] = f2bf((d[r] + bias) * mk32[tok]);   // mask fold
        }
      } else {
        const float bias = bv[out];
        #pragma unroll
        for (int r = 0; r < 4; ++r) {
          const int tok = tokT * 16 + quad * 4 + r;
          vt[out][tok] = f2bf((d[r] + bias) * mk32[tok]);   // mask fold
        }
      }
    }
  }
  __syncthreads();

  // qg vector store
  {
    const int tok = tid >> 3, c8 = (tid & 7) * 8;
    *(short8*)(qg + (long)(t0 + tok) * 64 + c8) = *(const short8*)(&qt[tok][c8]);
  }

  const long tile = (long)b * 288 + (n0 >> 5);
  {
    const int slot = tid >> 6, l = tid & 63;
    const int m = l & 15, qd = l >> 4, sub = slot >> 1, ss = slot & 1;
    const short8 v8 = *(const short8*)(&kt[sub * 16 + m][ss * 32 + qd * 8]);
    *(short8*)(ksw + tile * 2048 + tid * 8) = v8;
  }
  {
    // V with key-slot permutation: slot (qd, j): j<4 -> key 4qd+j (sub0),
    // j>=4 -> key 16+4qd+(j-4) (sub1). Two contiguous b64 reads.
    const int f = tid >> 6, l = tid & 63;
    const int m = l & 15, qd = l >> 4;
    const short4v lo = *(const short4v*)(&vt[f * 16 + m][qd * 4]);
    const short4v hi = *(const short4v*)(&vt[f * 16 + m][16 + qd * 4]);
    short8 v8;
    v8[0] = lo[0]; v8[1] = lo[1]; v8[2] = lo[2]; v8[3] = lo[3];
    v8[4] = hi[0]; v8[5] = hi[1]; v8[6] = hi[2]; v8[7] = hi[3];
    *(short8*)(vsw + tile * 2048 + tid * 8) = v8;
  }
}

// ======================================================================
// k_attn (ROUND-4): round-2 proven body (direct-global fragment reads,
// K ping-pong, no LDS staging in loop) + cvtpk/setprio micro-opts, at
// NS=16 splits for 6 blocks/CU (24 waves/CU; round-2 was grid-limited
// to 12). CRITICAL FIX vs round 3: __launch_bounds__(256,4) -- the
// (256,6) bound forced VGPR=40 and ~3.1 GB of scratch spills (705 us).
// Natural VGPR is ~84 (round 2), which ALREADY permits 6 waves/SIMD;
// no cap beyond 128 is needed or wanted.
// ======================================================================
template <int NS>
__global__ __launch_bounds__(256, 4) void k_attn(
    const unsigned short* __restrict__ qg, const unsigned short* __restrict__ ksw,
    const unsigned short* __restrict__ vsw,
    unsigned short* __restrict__ opart, float* __restrict__ lpart)
{
  constexpr int KITN = HW / NS / 32;   // tiles of 32 keys per split
  // LDS only for the epilogue per-wave fp32 transpose scratch
  __shared__ __align__(16) char smem[17408];

  const int tid = threadIdx.x, wid = tid >> 6, lane = tid & 63;
  const int mcol = lane & 15, quad = lane >> 4;
  const int bx = blockIdx.x;
  const int split = bx % NS, qidx = bx / NS;   // qidx 0..95
  const int b = qidx / 48, qt = qidx % 48;
  const long t0q = (long)b * HW + qt * 192 + wid * 48;

  const unsigned short* kswt = ksw + ((long)b * 288 + split * KITN) * 2048;
  const unsigned short* vswt = vsw + ((long)b * 288 + split * KITN) * 2048;

  short8 qf[3][2];
  #pragma unroll
  for (int g = 0; g < 3; ++g)
    #pragma unroll
    for (int s = 0; s < 2; ++s)
      qf[g][s] = *(const short8*)(qg + (t0q + g * 16 + mcol) * 64 + s * 32 + quad * 8);

  short8 ones8;
  #pragma unroll
  for (int i = 0; i < 8; ++i) ones8[i] = (short)0x3F80;   // bf16 1.0

  floatx4 oT[3][4], oL[3];
  #pragma unroll
  for (int g = 0; g < 3; ++g) {
    #pragma unroll
    for (int f = 0; f < 4; ++f) oT[g][f] = (floatx4){0.f,0.f,0.f,0.f};
    oL[g] = (floatx4){0.f,0.f,0.f,0.f};
  }

  // K register ping-pong: preload tile 0
  short8 ka[4], kb[4];
  #pragma unroll
  for (int s = 0; s < 4; ++s)
    ka[s] = *(const short8*)(kswt + (s * 64 + lane) * 8);

#define ATTN_ITER(IT, KCUR, KNXT)                                              \
  {                                                                            \
    short8 cv[4];                                                              \
    _Pragma("unroll")                                                          \
    for (int f = 0; f < 4; ++f)                                                \
      cv[f] = *(const short8*)(vswt + (IT) * 2048 + (f * 64 + lane) * 8);      \
    if ((IT) + 1 < KITN) {                                                     \
      _Pragma("unroll")                                                        \
      for (int s = 0; s < 4; ++s)                                              \
        KNXT[s] = *(const short8*)(kswt + ((IT) + 1) * 2048 + (s * 64 + lane) * 8); \
    }                                                                          \
    short8 pf[3];                                                              \
    _Pragma("unroll")                                                          \
    for (int g = 0; g < 3; ++g) {                                              \
      floatx4 s0 = (floatx4){0.f,0.f,0.f,0.f}, s1 = (floatx4){0.f,0.f,0.f,0.f};\
      __builtin_amdgcn_s_setprio(1);                                           \
      s0 = __builtin_amdgcn_mfma_f32_16x16x32_bf16(KCUR[0], qf[g][0], s0, 0, 0, 0); \
      s0 = __builtin_amdgcn_mfma_f32_16x16x32_bf16(KCUR[1], qf[g][1], s0, 0, 0, 0); \
      s1 = __builtin_amdgcn_mfma_f32_16x16x32_bf16(KCUR[2], qf[g][0], s1, 0, 0, 0); \
      s1 = __builtin_amdgcn_mfma_f32_16x16x32_bf16(KCUR[3], qf[g][1], s1, 0, 0, 0); \
      __builtin_amdgcn_s_setprio(0);                                           \
      int4v pv;                                                                \
      pv[0] = cvtpk(EXP2F(s0[0]), EXP2F(s0[1]));                               \
      pv[1] = cvtpk(EXP2F(s0[2]), EXP2F(s0[3]));                               \
      pv[2] = cvtpk(EXP2F(s1[0]), EXP2F(s1[1]));                               \
      pv[3] = cvtpk(EXP2F(s1[2]), EXP2F(s1[3]));                               \
      pf[g] = __builtin_bit_cast(short8, pv);                                  \
      oL[g] = __builtin_amdgcn_mfma_f32_16x16x32_bf16(ones8, pf[g], oL[g], 0, 0, 0); \
    }                                                                          \
    __builtin_amdgcn_s_setprio(1);                                             \
    _Pragma("unroll")                                                          \
    for (int f = 0; f < 4; ++f) {                                              \
      _Pragma("unroll")                                                        \
      for (int g = 0; g < 3; ++g)                                              \
        oT[g][f] = __builtin_amdgcn_mfma_f32_16x16x32_bf16(cv[f], pf[g], oT[g][f], 0, 0, 0); \
    }                                                                          \
    __builtin_amdgcn_s_setprio(0);                                             \
  }

  for (int it = 0; it < KITN; it += 2) {   // KITN even (36 or 18)
    ATTN_ITER(it,     ka, kb);
    ATTN_ITER(it + 1, kb, ka);
  }
#undef ATTN_ITER

  // epilogue: per-wave fp32->bf16 transpose through LDS (per-wave
  // disjoint regions; intra-wave lockstep makes write->read safe)
  float* scr = (float*)smem + wid * 1088;    // 16 rows x 68
  #pragma unroll
  for (int g = 0; g < 3; ++g) {
    #pragma unroll
    for (int f = 0; f < 4; ++f)
      #pragma unroll
      for (int r = 0; r < 4; ++r)
        scr[(quad * 4 + r) * 68 + f * 16 + mcol] = oT[g][f][r];
    #pragma unroll
    for (int ps = 0; ps < 2; ++ps) {
      const int row = ps * 8 + (lane >> 3), cb = (lane & 7) * 8;
      const floatx4 a = *(const floatx4*)(scr + row * 68 + cb);
      const floatx4 c = *(const floatx4*)(scr + row * 68 + cb + 4);
      int4v pk;
      pk[0] = cvtpk(a[0], a[1]); pk[1] = cvtpk(a[2], a[3]);
      pk[2] = cvtpk(c[0], c[1]); pk[3] = cvtpk(c[2], c[3]);
      *(int4v*)(opart + ((long)split * NTOK + t0q + g * 16 + row) * 64 + cb) = pk;
    }
  }
  if (lane < 16) {   // quad 0 holds l[query=mcol] in oL[g][0]
    #pragma unroll
    for (int g = 0; g < 3; ++g)
      lpart[(long)split * NTOK + t0q + g * 16 + lane] = oL[g][0];
  }
}

// ======================================================================
// k_post: templated on NS (merge loop width); otherwise unchanged.
// ======================================================================
template <int NS>
__global__ __launch_bounds__(256) void k_post(
    const unsigned short* __restrict__ opart, const float* __restrict__ lpart,
    const unsigned short* __restrict__ h_bf, const float* __restrict__ maskf,
    const float* __restrict__ cntb,
    const unsigned short* __restrict__ wobf, const float* __restrict__ bo,
    const float* __restrict__ g2, const float* __restrict__ b2,
    const unsigned short* __restrict__ w1bf, const float* __restrict__ bf1,
    const unsigned short* __restrict__ w2bf, const float* __restrict__ bf2,
    float* __restrict__ out)
{
  __shared__ float          h2_lds[32 * 68];
  __shared__ unsigned short att_lds[32 * 72];
  __shared__ unsigned short hn_lds[32 * 72];
  __shared__ unsigned short g_lds[32 * 264];
  __shared__ float          ot_lds[32 * 68];
  __shared__ float          linv[32];
  __shared__ float          st_mu[32], st_rs[32];
  __shared__ float          nred[4];

  const int tid = threadIdx.x, wid = tid >> 6, lane = tid & 63;
  const int mcol = lane & 15, quad = lane >> 4;
  const int t0 = blockIdx.x * 32;
  const int b = t0 / HW, n0 = t0 % HW;

  // nmask = sum of this batch's 288 per-block counts
  {
    float cacc = 0.f;
    for (int i = tid; i < 288; i += 256) cacc += cntb[b * 288 + i];
    #pragma unroll
    for (int d = 1; d < 64; d <<= 1) cacc += __shfl_xor(cacc, d);
    if (lane == 0) nred[wid] = cacc;
  }

  const int tok = tid >> 3, c8 = (tid & 7) * 8;
  float o[8];
  #pragma unroll
  for (int i = 0; i < 8; ++i) o[i] = 0.f;
  #pragma unroll
  for (int s = 0; s < NS; ++s) {
    const short8 op = *(const short8*)(opart + ((long)s * NTOK + t0 + tok) * 64 + c8);
    #pragma unroll
    for (int i = 0; i < 8; ++i) o[i] += bf2f((unsigned short)op[i]);
  }
  const short8 hb8 = *(const short8*)(h_bf + (long)(t0 + tok) * 64 + c8);
  const floatx4 bo0 = *(const floatx4*)(bo + c8);
  const floatx4 bo1 = *(const floatx4*)(bo + c8 + 4);
  __syncthreads();

  if (tid < 32) {
    float l = -((nred[0] + nred[1]) + (nred[2] + nred[3]));   // mask-fold correction
    #pragma unroll
    for (int s = 0; s < NS; ++s) l += lpart[(long)s * NTOK + t0 + tid];
    linv[tid] = 1.0f / l;
  }
  __syncthreads();
  {
    const float sc = linv[tok];
    int4v av;
    av[0] = pk2(o[0]*sc, o[1]*sc); av[1] = pk2(o[2]*sc, o[3]*sc);
    av[2] = pk2(o[4]*sc, o[5]*sc); av[3] = pk2(o[6]*sc, o[7]*sc);
    *(int4v*)(att_lds + tok * 72 + c8) = av;
    floatx4 h20, h21;
    #pragma unroll
    for (int i = 0; i < 4; ++i) {
      h20[i] = bf2f((unsigned short)hb8[i])     + bo0[i];
      h21[i] = bf2f((unsigned short)hb8[i + 4]) + bo1[i];
    }
    *(floatx4*)(h2_lds + tok * 68 + c8)     = h20;
    *(floatx4*)(h2_lds + tok * 68 + c8 + 4) = h21;
  }
  __syncthreads();

  const int Mt = wid & 1, nbase = (wid >> 1) * 2;
  {
    const short8 aA0 = *(const short8*)(att_lds + (Mt * 16 + mcol) * 72 + quad * 8);
    const short8 aA1 = *(const short8*)(att_lds + (Mt * 16 + mcol) * 72 + 32 + quad * 8);
    #pragma unroll
    for (int nt = 0; nt < 2; ++nt) {
      const int nc = (nbase + nt) * 16;
      const short8 b0 = *(const short8*)(wobf + (nc + mcol) * 64 + quad * 8);
      const short8 b1 = *(const short8*)(wobf + (nc + mcol) * 64 + 32 + quad * 8);
      floatx4 d = (floatx4){0.f,0.f,0.f,0.f};
      d = __builtin_amdgcn_mfma_f32_16x16x32_bf16(aA0, b0, d, 0, 0, 0);
      d = __builtin_amdgcn_mfma_f32_16x16x32_bf16(aA1, b1, d, 0, 0, 0);
      #pragma unroll
      for (int r = 0; r < 4; ++r)
        h2_lds[(Mt * 16 + quad * 4 + r) * 68 + nc + mcol] += d[r];
    }
  }
  __syncthreads();

  {
    floatx4 v0 = *(const floatx4*)(h2_lds + tok * 68 + c8);
    floatx4 v1 = *(const floatx4*)(h2_lds + tok * 68 + c8 + 4);
    float s1 = (v0[0]+v0[1])+(v0[2]+v0[3]) + (v1[0]+v1[1])+(v1[2]+v1[3]);
    float s2 = (v0[0]*v0[0]+v0[1]*v0[1])+(v0[2]*v0[2]+v0[3]*v0[3])
             + (v1[0]*v1[0]+v1[1]*v1[1])+(v1[2]*v1[2]+v1[3]*v1[3]);
    #pragma unroll
    for (int d = 1; d < 8; d <<= 1) { s1 += __shfl_xor(s1, d); s2 += __shfl_xor(s2, d); }
    if ((tid & 7) == 0) {
      const float mu = s1 * (1.f / 64.f);
      const float var = s2 * (1.f / 64.f) - mu * mu;
      st_mu[tok] = mu; st_rs[tok] = rsqrtf(var + 1e-5f);
    }
  }
  __syncthreads();

  {
    const float mu = st_mu[tok], rs = st_rs[tok];
    const floatx4 v0 = *(const floatx4*)(h2_lds + tok * 68 + c8);
    const floatx4 v1 = *(const floatx4*)(h2_lds + tok * 68 + c8 + 4);
    const floatx4 ga = *(const floatx4*)(g2 + c8), gb = *(const floatx4*)(g2 + c8 + 4);
    const floatx4 ba = *(const floatx4*)(b2 + c8), bb = *(const floatx4*)(b2 + c8 + 4);
    float hn[8];
    #pragma unroll
    for (int i = 0; i < 4; ++i) {
      hn[i]     = (v0[i] - mu) * rs * ga[i] + ba[i];
      hn[i + 4] = (v1[i] - mu) * rs * gb[i] + bb[i];
    }
    int4v hv;
    hv[0] = pk2(hn[0], hn[1]); hv[1] = pk2(hn[2], hn[3]);
    hv[2] = pk2(hn[4], hn[5]); hv[3] = pk2(hn[6], hn[7]);
    *(int4v*)(hn_lds + tok * 72 + c8) = hv;
  }
  __syncthreads();

  {
    const short8 aA0 = *(const short8*)(hn_lds + (Mt * 16 + mcol) * 72 + quad * 8);
    const short8 aA1 = *(const short8*)(hn_lds + (Mt * 16 + mcol) * 72 + 32 + quad * 8);
    #pragma unroll
    for (int nt = 0; nt < 8; ++nt) {
      const int u0 = ((wid >> 1) * 8 + nt) * 16;
      const short8 b0 = *(const short8*)(w1bf + (u0 + mcol) * 64 + quad * 8);
      const short8 b1 = *(const short8*)(w1bf + (u0 + mcol) * 64 + 32 + quad * 8);
      floatx4 d = (floatx4){0.f,0.f,0.f,0.f};
      d = __builtin_amdgcn_mfma_f32_16x16x32_bf16(aA0, b0, d, 0, 0, 0);
      d = __builtin_amdgcn_mfma_f32_16x16x32_bf16(aA1, b1, d, 0, 0, 0);
      const float bf1v = bf1[u0 + mcol];
      #pragma unroll
      for (int r = 0; r < 4; ++r) {
        const float a = d[r] + bf1v;
        const float gl = 0.5f * a * (1.0f + erff(a * 0.70710678118654752f));
        g_lds[(Mt * 16 + quad * 4 + r) * 264 + u0 + mcol] = f2bf(gl);
      }
    }
  }
  __syncthreads();

  {
    floatx4 acc[2];
    acc[0] = (floatx4){0.f,0.f,0.f,0.f}; acc[1] = (floatx4){0.f,0.f,0.f,0.f};
    #pragma unroll
    for (int ks = 0; ks < 8; ++ks) {
      const short8 aA = *(const short8*)(g_lds + (Mt * 16 + mcol) * 264 + ks * 32 + quad * 8);
      #pragma unroll
      for (int nt = 0; nt < 2; ++nt) {
        const int nc = (nbase + nt) * 16;
        const short8 bB = *(const short8*)(w2bf + (nc + mcol) * 256 + ks * 32 + quad * 8);
        acc[nt] = __builtin_amdgcn_mfma_f32_16x16x32_bf16(aA, bB, acc[nt], 0, 0, 0);
      }
    }
    #pragma unroll
    for (int nt = 0; nt < 2; ++nt) {
      const int cc = (nbase + nt) * 16 + mcol;
      const float g2v = g2[cc], b2v = b2[cc], bf2v = bf2[cc];
      #pragma unroll
      for (int r = 0; r < 4; ++r) {
        const int tokr = Mt * 16 + quad * 4 + r;
        const float hn = (h2_lds[tokr * 68 + cc] - st_mu[tokr]) * st_rs[tokr] * g2v + b2v;
        const float o2 = (hn + acc[nt][r] + bf2v) * maskf[t0 + tokr];
        ot_lds[tokr * 68 + cc] = o2;
      }
    }
  }
  __syncthreads();

  {
    const int c = tid >> 2, tg = (tid & 3) * 8;
    floatx4 v0, v1;
    #pragma unroll
    for (int i = 0; i < 4; ++i) {
      v0[i] = ot_lds[(tg + i) * 68 + c];
      v1[i] = ot_lds[(tg + 4 + i) * 68 + c];
    }
    float* dst = out + ((long)b * 64 + c) * HW + n0 + tg;
    *(floatx4*)dst = v0;
    *(floatx4*)(dst + 4) = v1;
  }
}

// ======================================================================
extern "C" void kernel_launch(void* const* d_in, const int* in_sizes, int n_in,
                              void* d_out, int out_size, void* d_ws, size_t ws_size,
                              hipStream_t stream) {
  (void)in_sizes; (void)n_in; (void)out_size;
  const float* x   = (const float*)d_in[0];
  const int*   msk = (const int*)  d_in[1];
  const float* wq  = (const float*)d_in[2];
  const float* bq  = (const float*)d_in[3];
  const float* wk  = (const float*)d_in[4];
  const float* bk  = (const float*)d_in[5];
  const float* wv  = (const float*)d_in[6];
  const float* bv  = (const float*)d_in[7];
  const float* wo  = (const float*)d_in[8];
  const float* bo  = (const float*)d_in[9];
  const float* g1  = (const float*)d_in[10];
  const float* b1  = (const float*)d_in[11];
  const float* g2  = (const float*)d_in[12];
  const float* b2  = (const float*)d_in[13];
  const float* w1  = (const float*)d_in[14];
  const float* bf1 = (const float*)d_in[15];
  const float* w2  = (const float*)d_in[16];
  const float* bf2 = (const float*)d_in[17];
  float* out = (float*)d_out;

  // pick split count by available workspace (16 needs ~48.5 MB)
  auto ws_need = [](size_t S) -> size_t {
    return 4ull * 2359296 + S * NTOK * 64 * 2 + S * NTOK * 4
         + 73728 + 8192 + 32768 + 32768 + 2304;
  };
  const int S = (ws_size >= ws_need(16)) ? 16 : 8;

  char* ws = (char*)d_ws;
  size_t off = 0;
  unsigned short* h_bf  = (unsigned short*)(ws + off); off += 2359296;
  unsigned short* qg    = (unsigned short*)(ws + off); off += 2359296;
  unsigned short* ksw   = (unsigned short*)(ws + off); off += 2359296;
  unsigned short* vsw   = (unsigned short*)(ws + off); off += 2359296;
  unsigned short* opart = (unsigned short*)(ws + off); off += (size_t)S * NTOK * 64 * 2;
  float*          lpart = (float*)(ws + off);          off += (size_t)S * NTOK * 4;
  float*          maskf = (float*)(ws + off);          off += 73728;
  unsigned short* wobf  = (unsigned short*)(ws + off); off += 8192;
  unsigned short* w1bf  = (unsigned short*)(ws + off); off += 32768;
  unsigned short* w2bf  = (unsigned short*)(ws + off); off += 32768;
  float*          cntb  = (float*)(ws + off);          off += 2304;

  k_qkv<<<dim3(576), dim3(256), 0, stream>>>(
      x, wq, bq, wk, bk, wv, bv, g1, b1, msk, wo, w1, w2,
      h_bf, qg, ksw, vsw, maskf, wobf, w1bf, w2bf, cntb);
  if (S == 16) {
    k_attn<16><<<dim3(96 * 16), dim3(256), 0, stream>>>(qg, ksw, vsw, opart, lpart);
    k_post<16><<<dim3(576), dim3(256), 0, stream>>>(
        opart, lpart, h_bf, maskf, cntb, wobf, bo, g2, b2, w1bf, bf1, w2bf, bf2, out);
  } else {
    k_attn<8><<<dim3(96 * 8), dim3(256), 0, stream>>>(qg, ksw, vsw, opart, lpart);
    k_post<8><<<dim3(576), dim3(256), 0, stream>>>(
        opart, lpart, h_bf, maskf, cntb, wobf, bo, g2, b2, w1bf, bf1, w2bf, bf2, out);
  }
}

// Round 6
// 157.312 us; speedup vs baseline: 4.9630x; 2.5870x over previous
//
#include <hip/hip_runtime.h>

// ---- problem constants ----
#define HW     9216
#define NTOK   18432

typedef float  floatx4 __attribute__((ext_vector_type(4)));
typedef short  short8  __attribute__((ext_vector_type(8)));
typedef short  short4v __attribute__((ext_vector_type(4)));
typedef int    int4v   __attribute__((ext_vector_type(4)));

#if __has_builtin(__builtin_amdgcn_exp2f)
#define EXP2F(x) __builtin_amdgcn_exp2f(x)
#else
#define EXP2F(x) exp2f(x)
#endif

__device__ __forceinline__ unsigned short f2bf(float f) {   // RNE
  unsigned int u = __float_as_uint(f);
  u += 0x7fffu + ((u >> 16) & 1u);
  return (unsigned short)(u >> 16);
}
__device__ __forceinline__ float bf2f(unsigned short s) {
  return __uint_as_float(((unsigned int)s) << 16);
}
// pack two floats to bf16x2 (round-half-away) -- used in k_qkv/k_post
__device__ __forceinline__ int pk2(float a, float b) {
  unsigned ua = __float_as_uint(a) + 0x8000u;
  unsigned ub = __float_as_uint(b) + 0x8000u;
  return (int)((ua >> 16) | (ub & 0xffff0000u));
}
// single-instruction pack (RNE), gfx950 v_cvt_pk_bf16_f32: 5 VALU -> 1
__device__ __forceinline__ int cvtpk(float a, float b) {
  int r;
  asm("v_cvt_pk_bf16_f32 %0, %1, %2" : "=v"(r) : "v"(a), "v"(b));
  return r;
}

// ======================================================================
// k_qkv: UNCHANGED (LN1 + MFMA Q/K/V projections, weights staged bf16
// in LDS, vector stores; output formats frozen). Split-count agnostic.
// ======================================================================
__global__ __launch_bounds__(256) void k_qkv(
    const float* __restrict__ x,
    const float* __restrict__ wq, const float* __restrict__ bq,
    const float* __restrict__ wk, const float* __restrict__ bk,
    const float* __restrict__ wv, const float* __restrict__ bv,
    const float* __restrict__ g1, const float* __restrict__ b1,
    const int* __restrict__ mask,
    const float* __restrict__ wo, const float* __restrict__ w1,
    const float* __restrict__ w2,
    unsigned short* __restrict__ h_bf, unsigned short* __restrict__ qg,
    unsigned short* __restrict__ ksw, unsigned short* __restrict__ vsw,
    float* __restrict__ maskf, unsigned short* __restrict__ wobf,
    unsigned short* __restrict__ w1bf, unsigned short* __restrict__ w2bf,
    float* __restrict__ cntb)
{
  // overlay: x-tile (8448 B) lives only until LN is done; then the same
  // region holds the bf16 weights wb[3][64][72] (27648 B).
  __shared__ __align__(16) char usmem[27648];
  float (*xt)[33] = (float (*)[33])usmem;
  unsigned short (*wb)[64][72] = (unsigned short (*)[64][72])usmem;

  __shared__ unsigned short hq[32][72];   // h bf16 [tok][ch]
  __shared__ unsigned short kt[32][72];
  __shared__ unsigned short vt[64][40];
  __shared__ unsigned short qt[32][72];
  __shared__ float mk32[32];

  const int tid = threadIdx.x, wid = tid >> 6, c = tid & 63;
  const int mcol = c & 15, quad = c >> 4;
  const int bx = blockIdx.x;
  const int t0 = bx * 32;
  const int b  = t0 / HW, n0 = t0 % HW;

  if (tid < 32) {
    const float m = mask[t0 + tid] ? 1.f : 0.f;
    maskf[t0 + tid] = m;
    mk32[tid] = m;
  }
  // per-block masked-token count (wave 0 ballot; every slot written)
  if (wid == 0) {
    const bool mm = (c < 32) ? (mask[t0 + c] == 0) : false;
    const unsigned long long bal = __ballot(mm);
    if (c == 0) cntb[bx] = (float)__popcll(bal);
  }
  if (bx < 16)       { const int i = bx * 256 + tid;        wobf[i] = f2bf(wo[i]); }
  else if (bx < 80)  { const int i = (bx - 16) * 256 + tid; w1bf[i] = f2bf(w1[i]); }
  else if (bx < 144) { const int i = (bx - 80) * 256 + tid; w2bf[i] = f2bf(w2[i]); }

  #pragma unroll
  for (int p = 0; p < 2; ++p) {
    const int idx = p * 256 + tid;
    const int cc = idx >> 3, t4 = (idx & 7) * 4;
    const floatx4 v = *(const floatx4*)(x + ((long)b * 64 + cc) * HW + n0 + t4);
    xt[cc][t4 + 0] = v[0]; xt[cc][t4 + 1] = v[1];
    xt[cc][t4 + 2] = v[2]; xt[cc][t4 + 3] = v[3];
  }
  __syncthreads();

  // LN1: lane = channel, 8 tokens per wave (unchanged numerics)
  {
    const float g1v = g1[c], b1v = b1[c];
    #pragma unroll
    for (int tt = 0; tt < 8; ++tt) {
      const int tok = wid * 8 + tt;
      const float val = xt[c][tok];
      float s = val, q = val * val;
      #pragma unroll
      for (int d = 1; d < 64; d <<= 1) { s += __shfl_xor(s, d); q += __shfl_xor(q, d); }
      const float mu  = s * (1.f / 64.f);
      const float var = q * (1.f / 64.f) - mu * mu;
      const float hv  = (val - mu) * rsqrtf(var + 1e-5f) * g1v + b1v;
      hq[tok][c] = f2bf(hv);
    }
  }
  __syncthreads();   // hq ready; xt dead -> usmem reusable as wb

  // h_bf vector store (overlaps the wb fill below)
  {
    const int tok = tid >> 3, c8 = (tid & 7) * 8;
    *(short8*)(h_bf + (long)(t0 + tok) * 64 + c8) = *(const short8*)(&hq[tok][c8]);
  }

  // stage wq/wk/wv as bf16 into LDS, fully coalesced (12 x 16B loads/thread)
  {
    auto conv = [&](const float* __restrict__ W, int mwi) {
      #pragma unroll
      for (int j = 0; j < 4; ++j) {
        const int idx4 = (j * 256 + tid) * 4;      // 0..4095 step 4
        const int o = idx4 >> 6, in4 = idx4 & 63;
        const floatx4 w4 = *(const floatx4*)(W + idx4);
        short4v s4;
        s4[0] = (short)f2bf(w4[0]); s4[1] = (short)f2bf(w4[1]);
        s4[2] = (short)f2bf(w4[2]); s4[3] = (short)f2bf(w4[3]);
        *(short4v*)(&wb[mwi][o][in4]) = s4;
      }
    };
    conv(wq, 0); conv(wk, 1); conv(wv, 2);
  }
  __syncthreads();

  // MFMA projections: 24 output tiles (3 mats x 2 tokTiles x 4 outTiles),
  // 6 per wave. D[tokT*16+quad*4+r][outT*16+mcol] = sum_k h[tok][k]*W[out][k].
  {
    const float QSC = 0.125f * 1.44269504088896f;   // C^-0.5 * log2(e)
    #pragma unroll
    for (int i = 0; i < 6; ++i) {
      const int t = wid * 6 + i;
      const int mat  = t >> 3;          // 0:Q 1:K 2:V (uniform per wave-iter)
      const int tokT = (t >> 2) & 1;
      const int outT = t & 3;
      const int out  = outT * 16 + mcol;
      const short8 A0 = *(const short8*)(&hq[tokT * 16 + mcol][quad * 8]);
      const short8 A1 = *(const short8*)(&hq[tokT * 16 + mcol][32 + quad * 8]);
      const short8 B0 = *(const short8*)(&wb[mat][out][quad * 8]);
      const short8 B1 = *(const short8*)(&wb[mat][out][32 + quad * 8]);
      floatx4 d = (floatx4){0.f, 0.f, 0.f, 0.f};
      d = __builtin_amdgcn_mfma_f32_16x16x32_bf16(A0, B0, d, 0, 0, 0);
      d = __builtin_amdgcn_mfma_f32_16x16x32_bf16(A1, B1, d, 0, 0, 0);
      if (mat == 0) {
        const float bias = bq[out];
        #pragma unroll
        for (int r = 0; r < 4; ++r) {
          const int tok = tokT * 16 + quad * 4 + r;
          qt[tok][out] = f2bf((d[r] + bias) * QSC);
        }
      } else if (mat == 1) {
        const float bias = bk[out];
        #pragma unroll
        for (int r = 0; r < 4; ++r) {
          const int tok = tokT * 16 + quad * 4 + r;
          kt[tok][out] = f2bf((d[r] + bias) * mk32[tok]);   // mask fold
        }
      } else {
        const float bias = bv[out];
        #pragma unroll
        for (int r = 0; r < 4; ++r) {
          const int tok = tokT * 16 + quad * 4 + r;
          vt[out][tok] = f2bf((d[r] + bias) * mk32[tok]);   // mask fold
        }
      }
    }
  }
  __syncthreads();

  // qg vector store
  {
    const int tok = tid >> 3, c8 = (tid & 7) * 8;
    *(short8*)(qg + (long)(t0 + tok) * 64 + c8) = *(const short8*)(&qt[tok][c8]);
  }

  const long tile = (long)b * 288 + (n0 >> 5);
  {
    const int slot = tid >> 6, l = tid & 63;
    const int m = l & 15, qd = l >> 4, sub = slot >> 1, ss = slot & 1;
    const short8 v8 = *(const short8*)(&kt[sub * 16 + m][ss * 32 + qd * 8]);
    *(short8*)(ksw + tile * 2048 + tid * 8) = v8;
  }
  {
    // V with key-slot permutation: slot (qd, j): j<4 -> key 4qd+j (sub0),
    // j>=4 -> key 16+4qd+(j-4) (sub1). Two contiguous b64 reads.
    const int f = tid >> 6, l = tid & 63;
    const int m = l & 15, qd = l >> 4;
    const short4v lo = *(const short4v*)(&vt[f * 16 + m][qd * 4]);
    const short4v hi = *(const short4v*)(&vt[f * 16 + m][16 + qd * 4]);
    short8 v8;
    v8[0] = lo[0]; v8[1] = lo[1]; v8[2] = lo[2]; v8[3] = lo[3];
    v8[4] = hi[0]; v8[5] = hi[1]; v8[6] = hi[2]; v8[7] = hi[3];
    *(short8*)(vsw + tile * 2048 + tid * 8) = v8;
  }
}

// ======================================================================
// k_attn (ROUND-5): round-2 proven body (direct-global fragment reads,
// K ping-pong, no LDS staging in loop) + cvtpk/setprio, NS=16 splits.
//
// LAUNCH-BOUNDS LAW (empirical, this toolchain): VGPR cap = 256 / min_waves.
//   (256,3) -> 84   (round 2: fits, 0 spill)
//   (256,4) -> 64   (round 4: 1.3 GB spill, 310 us)
//   (256,6) -> 40   (round 3: 3.1 GB spill, 705 us)
// So (256,3) is the ONLY bound whose cap >= the body's natural ~84 regs.
// Runtime occupancy is set by ACTUAL VGPR use: 84 regs -> floor(512/84)
// = 6 waves/SIMD, and the NS=16 grid (1536 blocks = 6 blocks/CU) supplies
// them. LDS 6 x 17 KB = 104 KB/CU fits.
// ======================================================================
template <int NS>
__global__ __launch_bounds__(256, 3) void k_attn(
    const unsigned short* __restrict__ qg, const unsigned short* __restrict__ ksw,
    const unsigned short* __restrict__ vsw,
    unsigned short* __restrict__ opart, float* __restrict__ lpart)
{
  constexpr int KITN = HW / NS / 32;   // tiles of 32 keys per split
  // LDS only for the epilogue per-wave fp32 transpose scratch
  __shared__ __align__(16) char smem[17408];

  const int tid = threadIdx.x, wid = tid >> 6, lane = tid & 63;
  const int mcol = lane & 15, quad = lane >> 4;
  const int bx = blockIdx.x;
  const int split = bx % NS, qidx = bx / NS;   // qidx 0..95
  const int b = qidx / 48, qt = qidx % 48;
  const long t0q = (long)b * HW + qt * 192 + wid * 48;

  const unsigned short* kswt = ksw + ((long)b * 288 + split * KITN) * 2048;
  const unsigned short* vswt = vsw + ((long)b * 288 + split * KITN) * 2048;

  short8 qf[3][2];
  #pragma unroll
  for (int g = 0; g < 3; ++g)
    #pragma unroll
    for (int s = 0; s < 2; ++s)
      qf[g][s] = *(const short8*)(qg + (t0q + g * 16 + mcol) * 64 + s * 32 + quad * 8);

  short8 ones8;
  #pragma unroll
  for (int i = 0; i < 8; ++i) ones8[i] = (short)0x3F80;   // bf16 1.0

  floatx4 oT[3][4], oL[3];
  #pragma unroll
  for (int g = 0; g < 3; ++g) {
    #pragma unroll
    for (int f = 0; f < 4; ++f) oT[g][f] = (floatx4){0.f,0.f,0.f,0.f};
    oL[g] = (floatx4){0.f,0.f,0.f,0.f};
  }

  // K register ping-pong: preload tile 0
  short8 ka[4], kb[4];
  #pragma unroll
  for (int s = 0; s < 4; ++s)
    ka[s] = *(const short8*)(kswt + (s * 64 + lane) * 8);

#define ATTN_ITER(IT, KCUR, KNXT)                                              \
  {                                                                            \
    short8 cv[4];                                                              \
    _Pragma("unroll")                                                          \
    for (int f = 0; f < 4; ++f)                                                \
      cv[f] = *(const short8*)(vswt + (IT) * 2048 + (f * 64 + lane) * 8);      \
    if ((IT) + 1 < KITN) {                                                     \
      _Pragma("unroll")                                                        \
      for (int s = 0; s < 4; ++s)                                              \
        KNXT[s] = *(const short8*)(kswt + ((IT) + 1) * 2048 + (s * 64 + lane) * 8); \
    }                                                                          \
    short8 pf[3];                                                              \
    _Pragma("unroll")                                                          \
    for (int g = 0; g < 3; ++g) {                                              \
      floatx4 s0 = (floatx4){0.f,0.f,0.f,0.f}, s1 = (floatx4){0.f,0.f,0.f,0.f};\
      __builtin_amdgcn_s_setprio(1);                                           \
      s0 = __builtin_amdgcn_mfma_f32_16x16x32_bf16(KCUR[0], qf[g][0], s0, 0, 0, 0); \
      s0 = __builtin_amdgcn_mfma_f32_16x16x32_bf16(KCUR[1], qf[g][1], s0, 0, 0, 0); \
      s1 = __builtin_amdgcn_mfma_f32_16x16x32_bf16(KCUR[2], qf[g][0], s1, 0, 0, 0); \
      s1 = __builtin_amdgcn_mfma_f32_16x16x32_bf16(KCUR[3], qf[g][1], s1, 0, 0, 0); \
      __builtin_amdgcn_s_setprio(0);                                           \
      int4v pv;                                                                \
      pv[0] = cvtpk(EXP2F(s0[0]), EXP2F(s0[1]));                               \
      pv[1] = cvtpk(EXP2F(s0[2]), EXP2F(s0[3]));                               \
      pv[2] = cvtpk(EXP2F(s1[0]), EXP2F(s1[1]));                               \
      pv[3] = cvtpk(EXP2F(s1[2]), EXP2F(s1[3]));                               \
      pf[g] = __builtin_bit_cast(short8, pv);                                  \
      oL[g] = __builtin_amdgcn_mfma_f32_16x16x32_bf16(ones8, pf[g], oL[g], 0, 0, 0); \
    }                                                                          \
    __builtin_amdgcn_s_setprio(1);                                             \
    _Pragma("unroll")                                                          \
    for (int f = 0; f < 4; ++f) {                                              \
      _Pragma("unroll")                                                        \
      for (int g = 0; g < 3; ++g)                                              \
        oT[g][f] = __builtin_amdgcn_mfma_f32_16x16x32_bf16(cv[f], pf[g], oT[g][f], 0, 0, 0); \
    }                                                                          \
    __builtin_amdgcn_s_setprio(0);                                             \
  }

  for (int it = 0; it < KITN; it += 2) {   // KITN even (36 or 18)
    ATTN_ITER(it,     ka, kb);
    ATTN_ITER(it + 1, kb, ka);
  }
#undef ATTN_ITER

  // epilogue: per-wave fp32->bf16 transpose through LDS (per-wave
  // disjoint regions; intra-wave lockstep makes write->read safe)
  float* scr = (float*)smem + wid * 1088;    // 16 rows x 68
  #pragma unroll
  for (int g = 0; g < 3; ++g) {
    #pragma unroll
    for (int f = 0; f < 4; ++f)
      #pragma unroll
      for (int r = 0; r < 4; ++r)
        scr[(quad * 4 + r) * 68 + f * 16 + mcol] = oT[g][f][r];
    #pragma unroll
    for (int ps = 0; ps < 2; ++ps) {
      const int row = ps * 8 + (lane >> 3), cb = (lane & 7) * 8;
      const floatx4 a = *(const floatx4*)(scr + row * 68 + cb);
      const floatx4 c = *(const floatx4*)(scr + row * 68 + cb + 4);
      int4v pk;
      pk[0] = cvtpk(a[0], a[1]); pk[1] = cvtpk(a[2], a[3]);
      pk[2] = cvtpk(c[0], c[1]); pk[3] = cvtpk(c[2], c[3]);
      *(int4v*)(opart + ((long)split * NTOK + t0q + g * 16 + row) * 64 + cb) = pk;
    }
  }
  if (lane < 16) {   // quad 0 holds l[query=mcol] in oL[g][0]
    #pragma unroll
    for (int g = 0; g < 3; ++g)
      lpart[(long)split * NTOK + t0q + g * 16 + lane] = oL[g][0];
  }
}

// ======================================================================
// k_post: templated on NS (merge loop width); otherwise unchanged.
// ======================================================================
template <int NS>
__global__ __launch_bounds__(256) void k_post(
    const unsigned short* __restrict__ opart, const float* __restrict__ lpart,
    const unsigned short* __restrict__ h_bf, const float* __restrict__ maskf,
    const float* __restrict__ cntb,
    const unsigned short* __restrict__ wobf, const float* __restrict__ bo,
    const float* __restrict__ g2, const float* __restrict__ b2,
    const unsigned short* __restrict__ w1bf, const float* __restrict__ bf1,
    const unsigned short* __restrict__ w2bf, const float* __restrict__ bf2,
    float* __restrict__ out)
{
  __shared__ float          h2_lds[32 * 68];
  __shared__ unsigned short att_lds[32 * 72];
  __shared__ unsigned short hn_lds[32 * 72];
  __shared__ unsigned short g_lds[32 * 264];
  __shared__ float          ot_lds[32 * 68];
  __shared__ float          linv[32];
  __shared__ float          st_mu[32], st_rs[32];
  __shared__ float          nred[4];

  const int tid = threadIdx.x, wid = tid >> 6, lane = tid & 63;
  const int mcol = lane & 15, quad = lane >> 4;
  const int t0 = blockIdx.x * 32;
  const int b = t0 / HW, n0 = t0 % HW;

  // nmask = sum of this batch's 288 per-block counts
  {
    float cacc = 0.f;
    for (int i = tid; i < 288; i += 256) cacc += cntb[b * 288 + i];
    #pragma unroll
    for (int d = 1; d < 64; d <<= 1) cacc += __shfl_xor(cacc, d);
    if (lane == 0) nred[wid] = cacc;
  }

  const int tok = tid >> 3, c8 = (tid & 7) * 8;
  float o[8];
  #pragma unroll
  for (int i = 0; i < 8; ++i) o[i] = 0.f;
  #pragma unroll
  for (int s = 0; s < NS; ++s) {
    const short8 op = *(const short8*)(opart + ((long)s * NTOK + t0 + tok) * 64 + c8);
    #pragma unroll
    for (int i = 0; i < 8; ++i) o[i] += bf2f((unsigned short)op[i]);
  }
  const short8 hb8 = *(const short8*)(h_bf + (long)(t0 + tok) * 64 + c8);
  const floatx4 bo0 = *(const floatx4*)(bo + c8);
  const floatx4 bo1 = *(const floatx4*)(bo + c8 + 4);
  __syncthreads();

  if (tid < 32) {
    float l = -((nred[0] + nred[1]) + (nred[2] + nred[3]));   // mask-fold correction
    #pragma unroll
    for (int s = 0; s < NS; ++s) l += lpart[(long)s * NTOK + t0 + tid];
    linv[tid] = 1.0f / l;
  }
  __syncthreads();
  {
    const float sc = linv[tok];
    int4v av;
    av[0] = pk2(o[0]*sc, o[1]*sc); av[1] = pk2(o[2]*sc, o[3]*sc);
    av[2] = pk2(o[4]*sc, o[5]*sc); av[3] = pk2(o[6]*sc, o[7]*sc);
    *(int4v*)(att_lds + tok * 72 + c8) = av;
    floatx4 h20, h21;
    #pragma unroll
    for (int i = 0; i < 4; ++i) {
      h20[i] = bf2f((unsigned short)hb8[i])     + bo0[i];
      h21[i] = bf2f((unsigned short)hb8[i + 4]) + bo1[i];
    }
    *(floatx4*)(h2_lds + tok * 68 + c8)     = h20;
    *(floatx4*)(h2_lds + tok * 68 + c8 + 4) = h21;
  }
  __syncthreads();

  const int Mt = wid & 1, nbase = (wid >> 1) * 2;
  {
    const short8 aA0 = *(const short8*)(att_lds + (Mt * 16 + mcol) * 72 + quad * 8);
    const short8 aA1 = *(const short8*)(att_lds + (Mt * 16 + mcol) * 72 + 32 + quad * 8);
    #pragma unroll
    for (int nt = 0; nt < 2; ++nt) {
      const int nc = (nbase + nt) * 16;
      const short8 b0 = *(const short8*)(wobf + (nc + mcol) * 64 + quad * 8);
      const short8 b1 = *(const short8*)(wobf + (nc + mcol) * 64 + 32 + quad * 8);
      floatx4 d = (floatx4){0.f,0.f,0.f,0.f};
      d = __builtin_amdgcn_mfma_f32_16x16x32_bf16(aA0, b0, d, 0, 0, 0);
      d = __builtin_amdgcn_mfma_f32_16x16x32_bf16(aA1, b1, d, 0, 0, 0);
      #pragma unroll
      for (int r = 0; r < 4; ++r)
        h2_lds[(Mt * 16 + quad * 4 + r) * 68 + nc + mcol] += d[r];
    }
  }
  __syncthreads();

  {
    floatx4 v0 = *(const floatx4*)(h2_lds + tok * 68 + c8);
    floatx4 v1 = *(const floatx4*)(h2_lds + tok * 68 + c8 + 4);
    float s1 = (v0[0]+v0[1])+(v0[2]+v0[3]) + (v1[0]+v1[1])+(v1[2]+v1[3]);
    float s2 = (v0[0]*v0[0]+v0[1]*v0[1])+(v0[2]*v0[2]+v0[3]*v0[3])
             + (v1[0]*v1[0]+v1[1]*v1[1])+(v1[2]*v1[2]+v1[3]*v1[3]);
    #pragma unroll
    for (int d = 1; d < 8; d <<= 1) { s1 += __shfl_xor(s1, d); s2 += __shfl_xor(s2, d); }
    if ((tid & 7) == 0) {
      const float mu = s1 * (1.f / 64.f);
      const float var = s2 * (1.f / 64.f) - mu * mu;
      st_mu[tok] = mu; st_rs[tok] = rsqrtf(var + 1e-5f);
    }
  }
  __syncthreads();

  {
    const float mu = st_mu[tok], rs = st_rs[tok];
    const floatx4 v0 = *(const floatx4*)(h2_lds + tok * 68 + c8);
    const floatx4 v1 = *(const floatx4*)(h2_lds + tok * 68 + c8 + 4);
    const floatx4 ga = *(const floatx4*)(g2 + c8), gb = *(const floatx4*)(g2 + c8 + 4);
    const floatx4 ba = *(const floatx4*)(b2 + c8), bb = *(const floatx4*)(b2 + c8 + 4);
    float hn[8];
    #pragma unroll
    for (int i = 0; i < 4; ++i) {
      hn[i]     = (v0[i] - mu) * rs * ga[i] + ba[i];
      hn[i + 4] = (v1[i] - mu) * rs * gb[i] + bb[i];
    }
    int4v hv;
    hv[0] = pk2(hn[0], hn[1]); hv[1] = pk2(hn[2], hn[3]);
    hv[2] = pk2(hn[4], hn[5]); hv[3] = pk2(hn[6], hn[7]);
    *(int4v*)(hn_lds + tok * 72 + c8) = hv;
  }
  __syncthreads();

  {
    const short8 aA0 = *(const short8*)(hn_lds + (Mt * 16 + mcol) * 72 + quad * 8);
    const short8 aA1 = *(const short8*)(hn_lds + (Mt * 16 + mcol) * 72 + 32 + quad * 8);
    #pragma unroll
    for (int nt = 0; nt < 8; ++nt) {
      const int u0 = ((wid >> 1) * 8 + nt) * 16;
      const short8 b0 = *(const short8*)(w1bf + (u0 + mcol) * 64 + quad * 8);
      const short8 b1 = *(const short8*)(w1bf + (u0 + mcol) * 64 + 32 + quad * 8);
      floatx4 d = (floatx4){0.f,0.f,0.f,0.f};
      d = __builtin_amdgcn_mfma_f32_16x16x32_bf16(aA0, b0, d, 0, 0, 0);
      d = __builtin_amdgcn_mfma_f32_16x16x32_bf16(aA1, b1, d, 0, 0, 0);
      const float bf1v = bf1[u0 + mcol];
      #pragma unroll
      for (int r = 0; r < 4; ++r) {
        const float a = d[r] + bf1v;
        const float gl = 0.5f * a * (1.0f + erff(a * 0.70710678118654752f));
        g_lds[(Mt * 16 + quad * 4 + r) * 264 + u0 + mcol] = f2bf(gl);
      }
    }
  }
  __syncthreads();

  {
    floatx4 acc[2];
    acc[0] = (floatx4){0.f,0.f,0.f,0.f}; acc[1] = (floatx4){0.f,0.f,0.f,0.f};
    #pragma unroll
    for (int ks = 0; ks < 8; ++ks) {
      const short8 aA = *(const short8*)(g_lds + (Mt * 16 + mcol) * 264 + ks * 32 + quad * 8);
      #pragma unroll
      for (int nt = 0; nt < 2; ++nt) {
        const int nc = (nbase + nt) * 16;
        const short8 bB = *(const short8*)(w2bf + (nc + mcol) * 256 + ks * 32 + quad * 8);
        acc[nt] = __builtin_amdgcn_mfma_f32_16x16x32_bf16(aA, bB, acc[nt], 0, 0, 0);
      }
    }
    #pragma unroll
    for (int nt = 0; nt < 2; ++nt) {
      const int cc = (nbase + nt) * 16 + mcol;
      const float g2v = g2[cc], b2v = b2[cc], bf2v = bf2[cc];
      #pragma unroll
      for (int r = 0; r < 4; ++r) {
        const int tokr = Mt * 16 + quad * 4 + r;
        const float hn = (h2_lds[tokr * 68 + cc] - st_mu[tokr]) * st_rs[tokr] * g2v + b2v;
        const float o2 = (hn + acc[nt][r] + bf2v) * maskf[t0 + tokr];
        ot_lds[tokr * 68 + cc] = o2;
      }
    }
  }
  __syncthreads();

  {
    const int c = tid >> 2, tg = (tid & 3) * 8;
    floatx4 v0, v1;
    #pragma unroll
    for (int i = 0; i < 4; ++i) {
      v0[i] = ot_lds[(tg + i) * 68 + c];
      v1[i] = ot_lds[(tg + 4 + i) * 68 + c];
    }
    float* dst = out + ((long)b * 64 + c) * HW + n0 + tg;
    *(floatx4*)dst = v0;
    *(floatx4*)(dst + 4) = v1;
  }
}

// ======================================================================
extern "C" void kernel_launch(void* const* d_in, const int* in_sizes, int n_in,
                              void* d_out, int out_size, void* d_ws, size_t ws_size,
                              hipStream_t stream) {
  (void)in_sizes; (void)n_in; (void)out_size;
  const float* x   = (const float*)d_in[0];
  const int*   msk = (const int*)  d_in[1];
  const float* wq  = (const float*)d_in[2];
  const float* bq  = (const float*)d_in[3];
  const float* wk  = (const float*)d_in[4];
  const float* bk  = (const float*)d_in[5];
  const float* wv  = (const float*)d_in[6];
  const float* bv  = (const float*)d_in[7];
  const float* wo  = (const float*)d_in[8];
  const float* bo  = (const float*)d_in[9];
  const float* g1  = (const float*)d_in[10];
  const float* b1  = (const float*)d_in[11];
  const float* g2  = (const float*)d_in[12];
  const float* b2  = (const float*)d_in[13];
  const float* w1  = (const float*)d_in[14];
  const float* bf1 = (const float*)d_in[15];
  const float* w2  = (const float*)d_in[16];
  const float* bf2 = (const float*)d_in[17];
  float* out = (float*)d_out;

  // pick split count by available workspace (16 needs ~48.5 MB)
  auto ws_need = [](size_t S) -> size_t {
    return 4ull * 2359296 + S * NTOK * 64 * 2 + S * NTOK * 4
         + 73728 + 8192 + 32768 + 32768 + 2304;
  };
  const int S = (ws_size >= ws_need(16)) ? 16 : 8;

  char* ws = (char*)d_ws;
  size_t off = 0;
  unsigned short* h_bf  = (unsigned short*)(ws + off); off += 2359296;
  unsigned short* qg    = (unsigned short*)(ws + off); off += 2359296;
  unsigned short* ksw   = (unsigned short*)(ws + off); off += 2359296;
  unsigned short* vsw   = (unsigned short*)(ws + off); off += 2359296;
  unsigned short* opart = (unsigned short*)(ws + off); off += (size_t)S * NTOK * 64 * 2;
  float*          lpart = (float*)(ws + off);          off += (size_t)S * NTOK * 4;
  float*          maskf = (float*)(ws + off);          off += 73728;
  unsigned short* wobf  = (unsigned short*)(ws + off); off += 8192;
  unsigned short* w1bf  = (unsigned short*)(ws + off); off += 32768;
  unsigned short* w2bf  = (unsigned short*)(ws + off); off += 32768;
  float*          cntb  = (float*)(ws + off);          off += 2304;

  k_qkv<<<dim3(576), dim3(256), 0, stream>>>(
      x, wq, bq, wk, bk, wv, bv, g1, b1, msk, wo, w1, w2,
      h_bf, qg, ksw, vsw, maskf, wobf, w1bf, w2bf, cntb);
  if (S == 16) {
    k_attn<16><<<dim3(96 * 16), dim3(256), 0, stream>>>(qg, ksw, vsw, opart, lpart);
    k_post<16><<<dim3(576), dim3(256), 0, stream>>>(
        opart, lpart, h_bf, maskf, cntb, wobf, bo, g2, b2, w1bf, bf1, w2bf, bf2, out);
  } else {
    k_attn<8><<<dim3(96 * 8), dim3(256), 0, stream>>>(qg, ksw, vsw, opart, lpart);
    k_post<8><<<dim3(576), dim3(256), 0, stream>>>(
        opart, lpart, h_bf, maskf, cntb, wobf, bo, g2, b2, w1bf, bf1, w2bf, bf2, out);
  }
}